// Round 10
// baseline (308.074 us; speedup 1.0000x reference)
//
#include <hip/hip_runtime.h>
#include <hip/hip_bf16.h>
#include <math.h>

#define GG 8192      // graphs = B*T
#define NODESN 23
#define KK 8
#define DIN 16
#define HH 128
#define RHH 128
#define EPG (NODESN*KK)   // 184 edges per graph
#define TTT 128
#define BBB 64

// ---------------------------------------------------------------------------
// DPP cross-lane add (VALU pipe -- NOT the DS pipe, unlike __shfl_xor).
// ---------------------------------------------------------------------------
template<int CTRL>
static __device__ __forceinline__ float dpp_add(float v) {
    int x = __builtin_amdgcn_update_dpp(0, __float_as_int(v), CTRL, 0xF, 0xF, true);
    return v + __int_as_float(x);
}
#define DPP_XOR1 0xB1   // quad_perm [1,0,3,2]
#define DPP_XOR2 0x4E   // quad_perm [2,3,0,1]

// ---------------------------------------------------------------------------
// Kernel 1: per-graph GCN up to hsum (layer-1 + neighborhood aggregation).
// ---------------------------------------------------------------------------
__global__ __launch_bounds__(256) void gcn_hsum(
    const float* __restrict__ x, const int* __restrict__ esrc,
    const int* __restrict__ runner,
    const float* __restrict__ W1, const float* __restrict__ b1,
    float* __restrict__ hsum_g)
{
    __shared__ float xs[NODESN * DIN];
    __shared__ int   srcs[EPG];
    __shared__ float t1[NODESN * HH];
    __shared__ float red[256];

    const int g   = blockIdx.x;
    const int tid = threadIdx.x;
    const int j   = tid & 127;
    const int nh  = tid >> 7;

    for (int i = tid; i < NODESN * DIN; i += 256) xs[i] = x[g * NODESN * DIN + i];
    for (int i = tid; i < EPG; i += 256)          srcs[i] = esrc[g * EPG + i] - g * NODESN;

    float w[DIN];
    #pragma unroll
    for (int k = 0; k < DIN; k++) w[k] = W1[k * HH + j];
    const float b1j = b1[j];
    __syncthreads();

    const int n0 = nh * 12;
    const int n1 = nh ? NODESN : 12;
    for (int n = n0; n < n1; n++) {
        float acc = 0.f;
        #pragma unroll
        for (int k = 0; k < DIN; k += 4) {
            float4 xv = *(const float4*)&xs[n * DIN + k];
            acc = fmaf(xv.x, w[k], fmaf(xv.y, w[k+1], fmaf(xv.z, w[k+2], fmaf(xv.w, w[k+3], acc))));
        }
        t1[n * HH + j] = acc;
    }
    __syncthreads();

    const int r = runner[g];
    float part = 0.f;
    for (int slot = nh; slot < 9; slot += 2) {
        int node = (slot < 8) ? srcs[r * KK + slot] : r;
        float acc = t1[node * HH + j];
        #pragma unroll
        for (int k = 0; k < KK; k++) acc += t1[srcs[node * KK + k] * HH + j];
        part += fmaxf(acc * (1.f / 9.f) + b1j, 0.f);
    }
    red[tid] = part;
    __syncthreads();
    if (tid < HH) hsum_g[(size_t)g * HH + tid] = red[tid] + red[tid + 128];
}

// ---------------------------------------------------------------------------
// Kernel 2: seq = relu((1/9) * hsum @ W2 + b2), 16 graphs per block.
// ---------------------------------------------------------------------------
__global__ __launch_bounds__(256) void seq_kernel(
    const float* __restrict__ hsum_g, const float* __restrict__ W2,
    const float* __restrict__ b2, float* __restrict__ seq)
{
    __shared__ float hs[16 * HH];
    const int tid = threadIdx.x;
    const int j = tid & 127, mh = tid >> 7;
    const size_t base = (size_t)blockIdx.x * 16 * HH;

    for (int v = tid; v < 16 * HH / 4; v += 256)
        ((float4*)hs)[v] = ((const float4*)(hsum_g + base))[v];
    __syncthreads();

    float acc[8];
    #pragma unroll
    for (int m = 0; m < 8; m++) acc[m] = 0.f;
    const float* hrow = hs + mh * 8 * HH;
    for (int k = 0; k < HH; k += 4) {
        float w0  = W2[(k+0)*HH + j];
        float w1  = W2[(k+1)*HH + j];
        float w2v = W2[(k+2)*HH + j];
        float w3  = W2[(k+3)*HH + j];
        #pragma unroll
        for (int m = 0; m < 8; m++) {
            float4 hv = *(const float4*)&hrow[m * HH + k];
            acc[m] = fmaf(hv.x, w0, fmaf(hv.y, w1, fmaf(hv.z, w2v, fmaf(hv.w, w3, acc[m]))));
        }
    }
    const float bj = b2[j];
    #pragma unroll
    for (int m = 0; m < 8; m++)
        seq[base + (size_t)(mh * 8 + m) * HH + j] = fmaxf(acc[m] * (1.f/9.f) + bj, 0.f);
}

// ---------------------------------------------------------------------------
// Kernel 3: transpose W_ih [384,128] -> WT [128,384]
// ---------------------------------------------------------------------------
__global__ void transpose_wih(const float* __restrict__ W, float* __restrict__ WT)
{
    int idx = blockIdx.x * 256 + threadIdx.x;
    if (idx < 3 * RHH * RHH) {
        int jj = idx / RHH, kk = idx - jj * RHH;
        WT[kk * (3 * RHH) + jj] = W[idx];
    }
}

// ---------------------------------------------------------------------------
// Kernel 4: xg = seq @ W_ih^T + b_ih   [8192,128]@[128,384]
// ---------------------------------------------------------------------------
__global__ __launch_bounds__(384) void xg_kernel(
    const float* __restrict__ seq, const float* __restrict__ WT,
    const float* __restrict__ b_ih, float* __restrict__ xg)
{
    const int tid = threadIdx.x;
    const int m0 = blockIdx.x * 8;
    const float* srow = seq + (size_t)m0 * RHH;
    float acc[8];
    const float bv = b_ih[tid];
    #pragma unroll
    for (int mi = 0; mi < 8; mi++) acc[mi] = bv;
    for (int k = 0; k < RHH; k += 4) {
        float w0 = WT[(k+0)*384 + tid];
        float w1 = WT[(k+1)*384 + tid];
        float w2 = WT[(k+2)*384 + tid];
        float w3 = WT[(k+3)*384 + tid];
        #pragma unroll
        for (int mi = 0; mi < 8; mi++) {
            float4 sv = *(const float4*)(srow + mi * RHH + k);
            acc[mi] = fmaf(sv.x, w0, fmaf(sv.y, w1, fmaf(sv.z, w2, fmaf(sv.w, w3, acc[mi]))));
        }
    }
    #pragma unroll
    for (int mi = 0; mi < 8; mi++)
        xg[(size_t)(m0 + mi) * 384 + tid] = acc[mi];
}

// ---------------------------------------------------------------------------
// Kernel 5: GRU, i-tiled + DS-minimized. 256 threads (4 waves) per batch elem.
// Thread (g,q): q = tid&3 (k-quarter, lane bits 0-1), g = tid>>2 -> owns TWO
// hidden units (g, g+64) sharing ONE 32-float h k-slice: each h float4 read
// feeds 6 dots (2 units x 3 gates). DS per step per CU: 32 h-reads (b128,
// phase-rotated, conflict-free) + 8 xg (b128 packed) + 8 writes = ~48 instr
// (R9: ~80). Reduction: pure DPP quad_perm (xor1+xor2), 0 DS ops. 1 block/CU
// via 84.5 KB LDS -> 4 waves = 1 wave/EU -> 512-VGPR budget for the 192
// weight floats/thread. houtb rows padded to 132 floats (proj was 8-way
// bank-conflicted at stride 128 -> R9's 557K SQ_LDS_BANK_CONFLICT).
// ---------------------------------------------------------------------------
#define CHUNK 32
#define HPAD 132
#define XGB_FLOATS (CHUNK * HH * 4)      // 16384 floats = 64 KB

__global__ __launch_bounds__(256)
__attribute__((amdgpu_waves_per_eu(1, 1)))
void gru_kernel(
    const float* __restrict__ xg, const float* __restrict__ W_hh,
    const float* __restrict__ b_hh, const float* __restrict__ Wp,
    const float* __restrict__ bp, float* __restrict__ out)
{
    __shared__ float xgbuf[XGB_FLOATS];          // [tl][i][{xr,xz,xn,pad}]
    __shared__ float houtb[(CHUNK + 2) * HPAD];  // rows 1..32 = h(t); row CHUNK = carry
    __shared__ float wps[2 * RHH + 2];           // Wp + bp
    // total 84.6 KB -> exactly 1 block/CU

    const int b   = blockIdx.x;
    const int tid = threadIdx.x;
    const int q   = tid & 3;       // k-quarter (quad_perm domain)
    const int g   = tid >> 2;      // unit group: units g and g+64

    const int i0 = g, i1 = g + 64;

    // ---- preload W_hh: rows {i0,i1} x gates {r,z,n}, cols [32q,32q+32),
    // phase-rotated (p = (m+2q)&7): 4 q-slices hit disjoint bank groups.
    float4 wr0[8], wz0[8], wn0[8], wr1[8], wz1[8], wn1[8];
    int lof[8];
    {
        const float* r0 = W_hh + (size_t)i0 * RHH;
        const float* z0 = r0 + (size_t)RHH * RHH;
        const float* n0 = z0 + (size_t)RHH * RHH;
        const float* r1 = W_hh + (size_t)i1 * RHH;
        const float* z1 = r1 + (size_t)RHH * RHH;
        const float* n1 = z1 + (size_t)RHH * RHH;
        #pragma unroll
        for (int m = 0; m < 8; m++) {
            int p = (m + 2 * q) & 7;
            int o = q * 32 + 4 * p;
            lof[m] = o;
            wr0[m] = *(const float4*)(r0 + o);
            wz0[m] = *(const float4*)(z0 + o);
            wn0[m] = *(const float4*)(n0 + o);
            wr1[m] = *(const float4*)(r1 + o);
            wz1[m] = *(const float4*)(z1 + o);
            wn1[m] = *(const float4*)(n1 + o);
        }
    }
    const float bhr0 = b_hh[i0], bhz0 = b_hh[RHH + i0], bhn0 = b_hh[2 * RHH + i0];
    const float bhr1 = b_hh[i1], bhz1 = b_hh[RHH + i1], bhn1 = b_hh[2 * RHH + i1];

    if (tid < 2 * RHH) wps[tid] = Wp[tid];
    if (tid < 2)       wps[2 * RHH + tid] = bp[tid];
    if (tid < HH)      houtb[CHUNK * HPAD + tid] = 0.f;   // carry row = h(-1) = 0
    float hp0 = 0.f, hp1 = 0.f;

    const float* xbase = xg + (size_t)b * TTT * 3 * RHH;
    float* outb = out + (size_t)b * TTT * 2;

    for (int c = 0; c < TTT / CHUNK; c++) {
        // ---- refill xgbuf for chunk c, repacking to [tl][i][{r,z,n,pad}]
        #pragma unroll 4
        for (int k2 = 0; k2 < 16; k2++) {
            int slot = tid + (k2 << 8);          // 0..4095
            int tl = slot >> 7, ii = slot & 127;
            const float* gsrc = xbase + (size_t)(c * CHUNK + tl) * 384 + ii;
            float4 v;
            v.x = gsrc[0]; v.y = gsrc[128]; v.z = gsrc[256]; v.w = 0.f;
            *(float4*)&xgbuf[slot << 2] = v;
        }
        // ---- project previous chunk: out = houtb[1..32] @ Wp + bp
        if (c > 0) {
            const int s  = tid & 3;              // 32-float k-slice (quad domain)
            const int cc = (tid >> 2) & 1;
            const int tl = tid >> 3;             // 0..31
            const float* hr = &houtb[(tl + 1) * HPAD + s * 32];
            float acc = 0.f;
            #pragma unroll
            for (int m = 0; m < 32; m += 4) {
                float4 hv = *(const float4*)(hr + m);
                int k = s * 32 + m;
                acc = fmaf(hv.x, wps[(k+0)*2 + cc],
                      fmaf(hv.y, wps[(k+1)*2 + cc],
                      fmaf(hv.z, wps[(k+2)*2 + cc],
                      fmaf(hv.w, wps[(k+3)*2 + cc], acc))));
            }
            acc = dpp_add<DPP_XOR1>(acc);
            acc = dpp_add<DPP_XOR2>(acc);
            if (s == 0)
                outb[((c - 1) * CHUNK + tl) * 2 + cc] = acc + wps[2 * RHH + cc];
        }
        __syncthreads();

        // ---- 32 steps; per step per CU: 32 h-reads + 8 xg + 8 writes
        for (int tl = 0; tl < CHUNK; tl++) {
            const float* hrow = &houtb[(tl == 0 ? CHUNK : tl) * HPAD];
            float4 x0 = *(const float4*)&xgbuf[(tl * HH + i0) << 2];
            float4 x1 = *(const float4*)&xgbuf[(tl * HH + i1) << 2];
            float ar0 = 0.f, az0 = 0.f, an0 = 0.f, ar1 = 0.f, az1 = 0.f, an1 = 0.f;
            #pragma unroll
            for (int m = 0; m < 8; m++) {
                float4 hv = *(const float4*)(hrow + lof[m]);
                ar0 = fmaf(hv.x, wr0[m].x, fmaf(hv.y, wr0[m].y, fmaf(hv.z, wr0[m].z, fmaf(hv.w, wr0[m].w, ar0))));
                az0 = fmaf(hv.x, wz0[m].x, fmaf(hv.y, wz0[m].y, fmaf(hv.z, wz0[m].z, fmaf(hv.w, wz0[m].w, az0))));
                an0 = fmaf(hv.x, wn0[m].x, fmaf(hv.y, wn0[m].y, fmaf(hv.z, wn0[m].z, fmaf(hv.w, wn0[m].w, an0))));
                ar1 = fmaf(hv.x, wr1[m].x, fmaf(hv.y, wr1[m].y, fmaf(hv.z, wr1[m].z, fmaf(hv.w, wr1[m].w, ar1))));
                az1 = fmaf(hv.x, wz1[m].x, fmaf(hv.y, wz1[m].y, fmaf(hv.z, wz1[m].z, fmaf(hv.w, wz1[m].w, az1))));
                an1 = fmaf(hv.x, wn1[m].x, fmaf(hv.y, wn1[m].y, fmaf(hv.z, wn1[m].z, fmaf(hv.w, wn1[m].w, an1))));
            }
            // q-reduction: pure VALU DPP butterfly; full sum lands in ALL lanes
            ar0 = dpp_add<DPP_XOR1>(ar0); ar0 = dpp_add<DPP_XOR2>(ar0);
            az0 = dpp_add<DPP_XOR1>(az0); az0 = dpp_add<DPP_XOR2>(az0);
            an0 = dpp_add<DPP_XOR1>(an0); an0 = dpp_add<DPP_XOR2>(an0);
            ar1 = dpp_add<DPP_XOR1>(ar1); ar1 = dpp_add<DPP_XOR2>(ar1);
            az1 = dpp_add<DPP_XOR1>(az1); az1 = dpp_add<DPP_XOR2>(az1);
            an1 = dpp_add<DPP_XOR1>(an1); an1 = dpp_add<DPP_XOR2>(an1);

            // gates for both units (uniform across q-lanes)
            {
                float sr = x0.x + ar0 + bhr0;
                float sz = x0.y + az0 + bhz0;
                float rg = 1.f / (1.f + __expf(-sr));
                float zg = 1.f / (1.f + __expf(-sz));
                float tv = fmaf(rg, an0 + bhn0, x0.z);
                tv = fminf(fmaxf(tv, -15.f), 15.f);
                float e2 = __expf(-2.f * tv);
                float ng = (1.f - e2) / (1.f + e2);
                hp0 = fmaf(zg, hp0, (1.f - zg) * ng);
            }
            {
                float sr = x1.x + ar1 + bhr1;
                float sz = x1.y + az1 + bhz1;
                float rg = 1.f / (1.f + __expf(-sr));
                float zg = 1.f / (1.f + __expf(-sz));
                float tv = fmaf(rg, an1 + bhn1, x1.z);
                tv = fminf(fmaxf(tv, -15.f), 15.f);
                float e2 = __expf(-2.f * tv);
                float ng = (1.f - e2) / (1.f + e2);
                hp1 = fmaf(zg, hp1, (1.f - zg) * ng);
            }
            if (q == 0) {
                houtb[(tl + 1) * HPAD + i0] = hp0;
                houtb[(tl + 1) * HPAD + i1] = hp1;
            }
            __syncthreads();
        }
    }

    // ---- project the last chunk
    {
        const int s  = tid & 3;
        const int cc = (tid >> 2) & 1;
        const int tl = tid >> 3;
        const float* hr = &houtb[(tl + 1) * HPAD + s * 32];
        float acc = 0.f;
        #pragma unroll
        for (int m = 0; m < 32; m += 4) {
            float4 hv = *(const float4*)(hr + m);
            int k = s * 32 + m;
            acc = fmaf(hv.x, wps[(k+0)*2 + cc],
                  fmaf(hv.y, wps[(k+1)*2 + cc],
                  fmaf(hv.z, wps[(k+2)*2 + cc],
                  fmaf(hv.w, wps[(k+3)*2 + cc], acc))));
        }
        acc = dpp_add<DPP_XOR1>(acc);
        acc = dpp_add<DPP_XOR2>(acc);
        if (s == 0)
            outb[((TTT / CHUNK - 1) * CHUNK + tl) * 2 + cc] = acc + wps[2 * RHH + cc];
    }
}

extern "C" void kernel_launch(void* const* d_in, const int* in_sizes, int n_in,
                              void* d_out, int out_size, void* d_ws, size_t ws_size,
                              hipStream_t stream)
{
    const float* x      = (const float*)d_in[0];
    const int*   eidx   = (const int*)d_in[1];
    const int*   runner = (const int*)d_in[2];
    const float* W1     = (const float*)d_in[3];
    const float* b1     = (const float*)d_in[4];
    const float* W2     = (const float*)d_in[5];
    const float* b2     = (const float*)d_in[6];
    const float* W_ih   = (const float*)d_in[7];
    const float* W_hh   = (const float*)d_in[8];
    const float* b_ih   = (const float*)d_in[9];
    const float* b_hh   = (const float*)d_in[10];
    const float* Wp     = (const float*)d_in[11];
    const float* bp     = (const float*)d_in[12];
    float* out = (float*)d_out;

    float* seq    = (float*)d_ws;                    // 8192*128   [0, 4 MB)
    float* xg     = seq + (size_t)GG * HH;           // 8192*384   [4, 16.6 MB)
    float* WT     = xg + (size_t)GG * 3 * RHH;       // 128*384
    float* hsum_g = xg;   // alias: dead before xg_kernel writes xg

    transpose_wih<<<192, 256, 0, stream>>>(W_ih, WT);
    gcn_hsum<<<GG, 256, 0, stream>>>(x, eidx, runner, W1, b1, hsum_g);
    seq_kernel<<<GG / 16, 256, 0, stream>>>(hsum_g, W2, b2, seq);
    xg_kernel<<<GG / 8, 384, 0, stream>>>(seq, WT, b_ih, xg);
    gru_kernel<<<BBB, 256, 0, stream>>>(xg, W_hh, b_hh, Wp, bp, out);
}

// Round 11
// 256.933 us; speedup vs baseline: 1.1990x; 1.1990x over previous
//
#include <hip/hip_runtime.h>
#include <hip/hip_bf16.h>
#include <math.h>

#define GG 8192      // graphs = B*T
#define NODESN 23
#define KK 8
#define DIN 16
#define HH 128
#define RHH 128
#define EPG (NODESN*KK)   // 184 edges per graph
#define TTT 128
#define BBB 64

// ---------------------------------------------------------------------------
// DPP cross-lane add (VALU pipe -- NOT the DS pipe, unlike __shfl_xor).
// ---------------------------------------------------------------------------
template<int CTRL>
static __device__ __forceinline__ float dpp_add(float v) {
    int x = __builtin_amdgcn_update_dpp(0, __float_as_int(v), CTRL, 0xF, 0xF, true);
    return v + __int_as_float(x);
}
#define DPP_XOR1 0xB1   // quad_perm [1,0,3,2]
#define DPP_XOR2 0x4E   // quad_perm [2,3,0,1]
#define DPP_SHL4 0x104  // fold lanes l+4 -> l within row (R9-proven)

// ---------------------------------------------------------------------------
// Kernel 1: per-graph GCN up to hsum. hsum is written into the first 128
// columns of the (otherwise dead) xg row for graph g -- saves a ws region.
// ---------------------------------------------------------------------------
__global__ __launch_bounds__(256) void gcn_hsum(
    const float* __restrict__ x, const int* __restrict__ esrc,
    const int* __restrict__ runner,
    const float* __restrict__ W1, const float* __restrict__ b1,
    float* __restrict__ xg /* hsum -> xg[g*384 + 0..127] */)
{
    __shared__ float xs[NODESN * DIN];
    __shared__ int   srcs[EPG];
    __shared__ float t1[NODESN * HH];
    __shared__ float red[256];

    const int g   = blockIdx.x;
    const int tid = threadIdx.x;
    const int j   = tid & 127;
    const int nh  = tid >> 7;

    for (int i = tid; i < NODESN * DIN; i += 256) xs[i] = x[g * NODESN * DIN + i];
    for (int i = tid; i < EPG; i += 256)          srcs[i] = esrc[g * EPG + i] - g * NODESN;

    float w[DIN];
    #pragma unroll
    for (int k = 0; k < DIN; k++) w[k] = W1[k * HH + j];
    const float b1j = b1[j];
    __syncthreads();

    const int n0 = nh * 12;
    const int n1 = nh ? NODESN : 12;
    for (int n = n0; n < n1; n++) {
        float acc = 0.f;
        #pragma unroll
        for (int k = 0; k < DIN; k += 4) {
            float4 xv = *(const float4*)&xs[n * DIN + k];
            acc = fmaf(xv.x, w[k], fmaf(xv.y, w[k+1], fmaf(xv.z, w[k+2], fmaf(xv.w, w[k+3], acc))));
        }
        t1[n * HH + j] = acc;
    }
    __syncthreads();

    const int r = runner[g];
    float part = 0.f;
    for (int slot = nh; slot < 9; slot += 2) {
        int node = (slot < 8) ? srcs[r * KK + slot] : r;
        float acc = t1[node * HH + j];
        #pragma unroll
        for (int k = 0; k < KK; k++) acc += t1[srcs[node * KK + k] * HH + j];
        part += fmaxf(acc * (1.f / 9.f) + b1j, 0.f);
    }
    red[tid] = part;
    __syncthreads();
    if (tid < HH) xg[(size_t)g * 384 + tid] = red[tid] + red[tid + 128];
}

// ---------------------------------------------------------------------------
// Kernel 2: pack W_ih [384,128] -> WTp [k/4][384][4] for b128 column loads.
// ---------------------------------------------------------------------------
__global__ void pack_wih(const float* __restrict__ W, float* __restrict__ WTp)
{
    int idx = blockIdx.x * 256 + threadIdx.x;
    if (idx < 3 * RHH * RHH) {
        int j = idx / RHH, k = idx - j * RHH;
        WTp[(k >> 2) * (384 * 4) + j * 4 + (k & 3)] = W[idx];
    }
}

// ---------------------------------------------------------------------------
// Kernel 3 (fused seq+xg): 16 graphs per block, 384 threads.
//   seq = relu((1/9) hsum @ W2 + b2)  -- stays in LDS, never touches HBM
//   xg  = seq @ W_ih^T + b_ih         -- overwrites the xg rows in-place
// hsum is read from xg[g*384 + 0..127] (written by gcn_hsum).
// ---------------------------------------------------------------------------
__global__ __launch_bounds__(384) void seqxg_kernel(
    float* __restrict__ xg, const float* __restrict__ W2,
    const float* __restrict__ b2, const float* __restrict__ WTp,
    const float* __restrict__ b_ih)
{
    __shared__ float hsb[16 * HH];   // hsum tile
    __shared__ float sqb[16 * HH];   // seq tile
    const int tid = threadIdx.x;
    const size_t row0 = (size_t)blockIdx.x * 16;

    // ---- stage hsum tile (f4 over 128-col prefix of each 384-col row)
    for (int v = tid; v < 16 * 32; v += 384) {
        int m = v >> 5, e = v & 31;
        ((float4*)hsb)[m * 32 + e] = *(const float4*)&xg[(row0 + m) * 384 + e * 4];
    }
    __syncthreads();

    // ---- seq: thread (j = tid&127, m0 = tid>>7) does rows m0, m0+3, ...
    {
        const int j = tid & 127, m0 = tid >> 7;
        const int nm = (m0 == 0) ? 6 : 5;
        float acc[6];
        #pragma unroll
        for (int t = 0; t < 6; t++) acc[t] = 0.f;
        for (int k = 0; k < HH; k += 4) {
            float w0 = W2[(k+0)*HH + j];
            float w1 = W2[(k+1)*HH + j];
            float w2 = W2[(k+2)*HH + j];
            float w3 = W2[(k+3)*HH + j];
            #pragma unroll
            for (int t = 0; t < 6; t++) {
                if (t < nm) {
                    float4 hv = *(const float4*)&hsb[(m0 + 3*t) * HH + k];
                    acc[t] = fmaf(hv.x, w0, fmaf(hv.y, w1, fmaf(hv.z, w2, fmaf(hv.w, w3, acc[t]))));
                }
            }
        }
        const float bj = b2[j];
        for (int t = 0; t < nm; t++)
            sqb[(m0 + 3*t) * HH + j] = fmaxf(acc[t] * (1.f/9.f) + bj, 0.f);
    }
    __syncthreads();

    // ---- xg: thread j2 = tid computes column j2 for all 16 rows
    {
        const int j2 = tid;
        float acc[16];
        const float bv = b_ih[j2];
        #pragma unroll
        for (int m = 0; m < 16; m++) acc[m] = bv;
        for (int k4 = 0; k4 < 32; k4++) {
            float4 wv = *(const float4*)&WTp[k4 * (384*4) + j2 * 4];
            #pragma unroll
            for (int m = 0; m < 16; m++) {
                float4 hv = *(const float4*)&sqb[m * HH + k4 * 4];
                acc[m] = fmaf(hv.x, wv.x, fmaf(hv.y, wv.y, fmaf(hv.z, wv.z, fmaf(hv.w, wv.w, acc[m]))));
            }
        }
        #pragma unroll
        for (int m = 0; m < 16; m++)
            xg[(row0 + m) * 384 + j2] = acc[m];
    }
}

// ---------------------------------------------------------------------------
// Kernel 4: GRU. 512 threads (8 waves, 2/SIMD -- R6/R9 sweet spot).
// Thread (g,q): q = tid&7 (k-eighth, lane bits 0..2), g = tid>>3 -> owns TWO
// ADJACENT units 2g, 2g+1 -> 96 W_hh floats/thread. DS per step per CU:
// 32 h-reads (b128, phase-rotated, <=2-way aliasing = free) + 16 xg (b128,
// [tl][i][rzn_] packed, conflict-free) + 8 writes (b64) = ~56 instr (R9: ~80,
// of which xg b128s were the 557K-conflict source). q-reduction: pure-VALU
// DPP xor1+xor2+row_shl4 (R9-proj-proven). Next chunk's xg prefetched into
// 24 VGPRs during the steps -> zero refill stall. 84.5 KB LDS -> 1 block/CU.
// ---------------------------------------------------------------------------
#define CHUNK 32
#define NCH (TTT / CHUNK)
#define HPAD 132
#define XGB_FLOATS (CHUNK * HH * 4)      // 16384 floats = 64 KB

__global__ __launch_bounds__(512)
__attribute__((amdgpu_waves_per_eu(2, 2)))
void gru_kernel(
    const float* __restrict__ xg, const float* __restrict__ W_hh,
    const float* __restrict__ b_hh, const float* __restrict__ Wp,
    const float* __restrict__ bp, float* __restrict__ out)
{
    __shared__ float xgbuf[XGB_FLOATS];          // [tl][i][{xr,xz,xn,pad}]
    __shared__ float houtb[(CHUNK + 2) * HPAD];  // rows 1..32 = h(t); row 32 = carry
    __shared__ float wps[2 * RHH + 2];           // Wp + bp

    const int b   = blockIdx.x;
    const int tid = threadIdx.x;
    const int q   = tid & 7;       // k-eighth (lane bits 0..2, DPP domain)
    const int g   = tid >> 3;      // unit pair index 0..63
    const int i0  = 2 * g, i1 = 2 * g + 1;

    // ---- preload W_hh: rows {i0,i1} x {r,z,n}, cols [16q,16q+16),
    // phase-rotated p=(m+q)&3 -> per-m banks distinct mod 2-way (free).
    float4 wr0[4], wz0[4], wn0[4], wr1[4], wz1[4], wn1[4];
    int lof[4];
    {
        const float* r0 = W_hh + (size_t)i0 * RHH;
        const float* z0 = r0 + (size_t)RHH * RHH;
        const float* n0 = z0 + (size_t)RHH * RHH;
        const float* r1 = W_hh + (size_t)i1 * RHH;
        const float* z1 = r1 + (size_t)RHH * RHH;
        const float* n1 = z1 + (size_t)RHH * RHH;
        #pragma unroll
        for (int m = 0; m < 4; m++) {
            int o = q * 16 + 4 * ((m + q) & 3);
            lof[m] = o;
            wr0[m] = *(const float4*)(r0 + o);
            wz0[m] = *(const float4*)(z0 + o);
            wn0[m] = *(const float4*)(n0 + o);
            wr1[m] = *(const float4*)(r1 + o);
            wz1[m] = *(const float4*)(z1 + o);
            wn1[m] = *(const float4*)(n1 + o);
        }
    }
    const float bhr0 = b_hh[i0], bhz0 = b_hh[RHH + i0], bhn0 = b_hh[2 * RHH + i0];
    const float bhr1 = b_hh[i1], bhz1 = b_hh[RHH + i1], bhn1 = b_hh[2 * RHH + i1];

    if (tid < 2 * RHH) wps[tid] = Wp[tid];
    if (tid < 2)       wps[2 * RHH + tid] = bp[tid];
    if (tid < HH)      houtb[CHUNK * HPAD + tid] = 0.f;   // carry = h(-1) = 0
    float hp0 = 0.f, hp1 = 0.f;

    const float* xbase = xg + (size_t)b * TTT * 3 * RHH;
    float* outb = out + (size_t)b * TTT * 2;

    // ---- prologue: prefetch chunk 0 into registers
    float pxr[8], pxz[8], pxn[8];
    #pragma unroll
    for (int k = 0; k < 8; k++) {
        int slot = tid + (k << 9);                 // 0..4095
        int tl = slot >> 7, ii = slot & 127;
        const float* p = xbase + (size_t)tl * 384 + ii;
        pxr[k] = p[0]; pxz[k] = p[128]; pxn[k] = p[256];
    }
    __syncthreads();

    for (int c = 0; c < NCH; c++) {
        // ---- write prefetched xg into LDS (repacked [tl][i][{r,z,n,pad}])
        #pragma unroll
        for (int k = 0; k < 8; k++) {
            int slot = tid + (k << 9);
            int tl = slot >> 7, ii = slot & 127;
            float4 v; v.x = pxr[k]; v.y = pxz[k]; v.z = pxn[k]; v.w = 0.f;
            *(float4*)&xgbuf[(tl << 9) + (ii << 2)] = v;
        }
        // ---- prefetch chunk c+1 (lands during the 32 steps)
        if (c + 1 < NCH) {
            #pragma unroll
            for (int k = 0; k < 8; k++) {
                int slot = tid + (k << 9);
                int tl = slot >> 7, ii = slot & 127;
                const float* p = xbase + (size_t)((c + 1) * CHUNK + tl) * 384 + ii;
                pxr[k] = p[0]; pxz[k] = p[128]; pxn[k] = p[256];
            }
        }
        // ---- project previous chunk: out = houtb[1..32] @ Wp + bp
        if (c > 0) {
            const int s  = tid & 7;              // 16-float k-slice (DPP domain)
            const int cc = (tid >> 3) & 1;
            const int tl = tid >> 4;             // 0..31
            const float* hr = &houtb[(tl + 1) * HPAD + s * 16];
            float acc = 0.f;
            #pragma unroll
            for (int jj = 0; jj < 4; jj++) {
                int mm = ((jj + s) & 3) << 2;    // bank-rotated within slice
                float4 hv = *(const float4*)(hr + mm);
                int k = s * 16 + mm;
                acc = fmaf(hv.x, wps[(k+0)*2 + cc],
                      fmaf(hv.y, wps[(k+1)*2 + cc],
                      fmaf(hv.z, wps[(k+2)*2 + cc],
                      fmaf(hv.w, wps[(k+3)*2 + cc], acc))));
            }
            acc = dpp_add<DPP_XOR1>(acc);
            acc = dpp_add<DPP_XOR2>(acc);
            acc = dpp_add<DPP_SHL4>(acc);
            if (s == 0)
                outb[((c - 1) * CHUNK + tl) * 2 + cc] = acc + wps[2 * RHH + cc];
        }
        __syncthreads();

        // ---- 32 steps; per CU per step: 32 h b128 + 16 xg b128 + 8 b64 wr
        for (int tl = 0; tl < CHUNK; tl++) {
            const float* hrow = &houtb[(tl == 0 ? CHUNK : tl) * HPAD];
            float ar0 = 0.f, az0 = 0.f, an0 = 0.f, ar1 = 0.f, az1 = 0.f, an1 = 0.f;
            #pragma unroll
            for (int m = 0; m < 4; m++) {
                float4 hv = *(const float4*)(hrow + lof[m]);
                ar0 = fmaf(hv.x, wr0[m].x, fmaf(hv.y, wr0[m].y, fmaf(hv.z, wr0[m].z, fmaf(hv.w, wr0[m].w, ar0))));
                az0 = fmaf(hv.x, wz0[m].x, fmaf(hv.y, wz0[m].y, fmaf(hv.z, wz0[m].z, fmaf(hv.w, wz0[m].w, az0))));
                an0 = fmaf(hv.x, wn0[m].x, fmaf(hv.y, wn0[m].y, fmaf(hv.z, wn0[m].z, fmaf(hv.w, wn0[m].w, an0))));
                ar1 = fmaf(hv.x, wr1[m].x, fmaf(hv.y, wr1[m].y, fmaf(hv.z, wr1[m].z, fmaf(hv.w, wr1[m].w, ar1))));
                az1 = fmaf(hv.x, wz1[m].x, fmaf(hv.y, wz1[m].y, fmaf(hv.z, wz1[m].z, fmaf(hv.w, wz1[m].w, az1))));
                an1 = fmaf(hv.x, wn1[m].x, fmaf(hv.y, wn1[m].y, fmaf(hv.z, wn1[m].z, fmaf(hv.w, wn1[m].w, an1))));
            }
            // xg reads issued after the critical h-reads
            float4 x0 = *(const float4*)&xgbuf[(tl << 9) + (i0 << 2)];
            float4 x1 = *(const float4*)&xgbuf[(tl << 9) + (i1 << 2)];

            // reduce over the 8 q-slices: pure VALU, valid in lanes q<4
            ar0 = dpp_add<DPP_XOR1>(ar0); ar0 = dpp_add<DPP_XOR2>(ar0); ar0 = dpp_add<DPP_SHL4>(ar0);
            az0 = dpp_add<DPP_XOR1>(az0); az0 = dpp_add<DPP_XOR2>(az0); az0 = dpp_add<DPP_SHL4>(az0);
            an0 = dpp_add<DPP_XOR1>(an0); an0 = dpp_add<DPP_XOR2>(an0); an0 = dpp_add<DPP_SHL4>(an0);
            ar1 = dpp_add<DPP_XOR1>(ar1); ar1 = dpp_add<DPP_XOR2>(ar1); ar1 = dpp_add<DPP_SHL4>(ar1);
            az1 = dpp_add<DPP_XOR1>(az1); az1 = dpp_add<DPP_XOR2>(az1); az1 = dpp_add<DPP_SHL4>(az1);
            an1 = dpp_add<DPP_XOR1>(an1); an1 = dpp_add<DPP_XOR2>(an1); an1 = dpp_add<DPP_SHL4>(an1);

            // gates (computed in all lanes; valid where q<4; q==0 publishes)
            {
                float sr = x0.x + ar0 + bhr0;
                float sz = x0.y + az0 + bhz0;
                float rg = 1.f / (1.f + __expf(-sr));
                float zg = 1.f / (1.f + __expf(-sz));
                float tv = fmaf(rg, an0 + bhn0, x0.z);
                tv = fminf(fmaxf(tv, -15.f), 15.f);
                float e2 = __expf(-2.f * tv);
                float ng = (1.f - e2) / (1.f + e2);
                hp0 = fmaf(zg, hp0, (1.f - zg) * ng);
            }
            {
                float sr = x1.x + ar1 + bhr1;
                float sz = x1.y + az1 + bhz1;
                float rg = 1.f / (1.f + __expf(-sr));
                float zg = 1.f / (1.f + __expf(-sz));
                float tv = fmaf(rg, an1 + bhn1, x1.z);
                tv = fminf(fmaxf(tv, -15.f), 15.f);
                float e2 = __expf(-2.f * tv);
                float ng = (1.f - e2) / (1.f + e2);
                hp1 = fmaf(zg, hp1, (1.f - zg) * ng);
            }
            if (q == 0) {
                float2 hw; hw.x = hp0; hw.y = hp1;
                *(float2*)&houtb[(tl + 1) * HPAD + i0] = hw;
            }
            __syncthreads();
        }
    }

    // ---- project the last chunk
    {
        const int s  = tid & 7;
        const int cc = (tid >> 3) & 1;
        const int tl = tid >> 4;
        const float* hr = &houtb[(tl + 1) * HPAD + s * 16];
        float acc = 0.f;
        #pragma unroll
        for (int jj = 0; jj < 4; jj++) {
            int mm = ((jj + s) & 3) << 2;
            float4 hv = *(const float4*)(hr + mm);
            int k = s * 16 + mm;
            acc = fmaf(hv.x, wps[(k+0)*2 + cc],
                  fmaf(hv.y, wps[(k+1)*2 + cc],
                  fmaf(hv.z, wps[(k+2)*2 + cc],
                  fmaf(hv.w, wps[(k+3)*2 + cc], acc))));
        }
        acc = dpp_add<DPP_XOR1>(acc);
        acc = dpp_add<DPP_XOR2>(acc);
        acc = dpp_add<DPP_SHL4>(acc);
        if (s == 0)
            outb[((NCH - 1) * CHUNK + tl) * 2 + cc] = acc + wps[2 * RHH + cc];
    }
}

extern "C" void kernel_launch(void* const* d_in, const int* in_sizes, int n_in,
                              void* d_out, int out_size, void* d_ws, size_t ws_size,
                              hipStream_t stream)
{
    const float* x      = (const float*)d_in[0];
    const int*   eidx   = (const int*)d_in[1];
    const int*   runner = (const int*)d_in[2];
    const float* W1     = (const float*)d_in[3];
    const float* b1     = (const float*)d_in[4];
    const float* W2     = (const float*)d_in[5];
    const float* b2     = (const float*)d_in[6];
    const float* W_ih   = (const float*)d_in[7];
    const float* W_hh   = (const float*)d_in[8];
    const float* b_ih   = (const float*)d_in[9];
    const float* b_hh   = (const float*)d_in[10];
    const float* Wp     = (const float*)d_in[11];
    const float* bp     = (const float*)d_in[12];
    float* out = (float*)d_out;

    float* xg  = (float*)d_ws;                       // 8192*384  [0, 12.6 MB)
    float* WTp = xg + (size_t)GG * 3 * RHH;          // 128*384*... packed

    pack_wih<<<192, 256, 0, stream>>>(W_ih, WTp);
    gcn_hsum<<<GG, 256, 0, stream>>>(x, eidx, runner, W1, b1, xg);
    seqxg_kernel<<<GG / 16, 384, 0, stream>>>(xg, W2, b2, WTp, b_ih);
    gru_kernel<<<BBB, 512, 0, stream>>>(xg, W_hh, b_hh, Wp, bp, out);
}

// Round 13
// 245.277 us; speedup vs baseline: 1.2560x; 1.0475x over previous
//
#include <hip/hip_runtime.h>
#include <hip/hip_bf16.h>
#include <math.h>

#define GG 8192      // graphs = B*T
#define NODESN 23
#define KK 8
#define DIN 16
#define HH 128
#define RHH 128
#define EPG (NODESN*KK)   // 184 edges per graph
#define TTT 128
#define BBB 64

typedef float v2f __attribute__((ext_vector_type(2)));

// ---------------------------------------------------------------------------
// DPP cross-lane add (VALU pipe -- NOT the DS pipe, unlike __shfl_xor).
// ---------------------------------------------------------------------------
template<int CTRL>
static __device__ __forceinline__ float dpp_add(float v) {
    int x = __builtin_amdgcn_update_dpp(0, __float_as_int(v), CTRL, 0xF, 0xF, true);
    return v + __int_as_float(x);
}
#define DPP_XOR1 0xB1   // quad_perm [1,0,3,2]
#define DPP_XOR2 0x4E   // quad_perm [2,3,0,1]

// ---------------------------------------------------------------------------
// Kernel 1: per-graph GCN up to hsum -> xg[g*384 + 0..127] (dead space reuse).
// ---------------------------------------------------------------------------
__global__ __launch_bounds__(256) void gcn_hsum(
    const float* __restrict__ x, const int* __restrict__ esrc,
    const int* __restrict__ runner,
    const float* __restrict__ W1, const float* __restrict__ b1,
    float* __restrict__ xg)
{
    __shared__ float xs[NODESN * DIN];
    __shared__ int   srcs[EPG];
    __shared__ float t1[NODESN * HH];
    __shared__ float red[256];

    const int g   = blockIdx.x;
    const int tid = threadIdx.x;
    const int j   = tid & 127;
    const int nh  = tid >> 7;

    for (int i = tid; i < NODESN * DIN; i += 256) xs[i] = x[g * NODESN * DIN + i];
    for (int i = tid; i < EPG; i += 256)          srcs[i] = esrc[g * EPG + i] - g * NODESN;

    float w[DIN];
    #pragma unroll
    for (int k = 0; k < DIN; k++) w[k] = W1[k * HH + j];
    const float b1j = b1[j];
    __syncthreads();

    const int n0 = nh * 12;
    const int n1 = nh ? NODESN : 12;
    for (int n = n0; n < n1; n++) {
        float acc = 0.f;
        #pragma unroll
        for (int k = 0; k < DIN; k += 4) {
            float4 xv = *(const float4*)&xs[n * DIN + k];
            acc = fmaf(xv.x, w[k], fmaf(xv.y, w[k+1], fmaf(xv.z, w[k+2], fmaf(xv.w, w[k+3], acc))));
        }
        t1[n * HH + j] = acc;
    }
    __syncthreads();

    const int r = runner[g];
    float part = 0.f;
    for (int slot = nh; slot < 9; slot += 2) {
        int node = (slot < 8) ? srcs[r * KK + slot] : r;
        float acc = t1[node * HH + j];
        #pragma unroll
        for (int k = 0; k < KK; k++) acc += t1[srcs[node * KK + k] * HH + j];
        part += fmaxf(acc * (1.f / 9.f) + b1j, 0.f);
    }
    red[tid] = part;
    __syncthreads();
    if (tid < HH) xg[(size_t)g * 384 + tid] = red[tid] + red[tid + 128];
}

// ---------------------------------------------------------------------------
// Kernel 2: pack W_ih [384,128] -> WTp [k/4][384][4] for b128 column loads.
// ---------------------------------------------------------------------------
__global__ void pack_wih(const float* __restrict__ W, float* __restrict__ WTp)
{
    int idx = blockIdx.x * 256 + threadIdx.x;
    if (idx < 3 * RHH * RHH) {
        int j = idx / RHH, k = idx - j * RHH;
        WTp[(k >> 2) * (384 * 4) + j * 4 + (k & 3)] = W[idx];
    }
}

// ---------------------------------------------------------------------------
// Kernel 3 (fused seq+xg): 16 graphs per block, 384 threads.
// ---------------------------------------------------------------------------
__global__ __launch_bounds__(384) void seqxg_kernel(
    float* __restrict__ xg, const float* __restrict__ W2,
    const float* __restrict__ b2, const float* __restrict__ WTp,
    const float* __restrict__ b_ih)
{
    __shared__ float hsb[16 * HH];
    __shared__ float sqb[16 * HH];
    const int tid = threadIdx.x;
    const size_t row0 = (size_t)blockIdx.x * 16;

    for (int v = tid; v < 16 * 32; v += 384) {
        int m = v >> 5, e = v & 31;
        ((float4*)hsb)[m * 32 + e] = *(const float4*)&xg[(row0 + m) * 384 + e * 4];
    }
    __syncthreads();

    {
        const int j = tid & 127, m0 = tid >> 7;
        const int nm = (m0 == 0) ? 6 : 5;
        float acc[6];
        #pragma unroll
        for (int t = 0; t < 6; t++) acc[t] = 0.f;
        for (int k = 0; k < HH; k += 4) {
            float w0 = W2[(k+0)*HH + j];
            float w1 = W2[(k+1)*HH + j];
            float w2 = W2[(k+2)*HH + j];
            float w3 = W2[(k+3)*HH + j];
            #pragma unroll
            for (int t = 0; t < 6; t++) {
                if (t < nm) {
                    float4 hv = *(const float4*)&hsb[(m0 + 3*t) * HH + k];
                    acc[t] = fmaf(hv.x, w0, fmaf(hv.y, w1, fmaf(hv.z, w2, fmaf(hv.w, w3, acc[t]))));
                }
            }
        }
        const float bj = b2[j];
        for (int t = 0; t < nm; t++)
            sqb[(m0 + 3*t) * HH + j] = fmaxf(acc[t] * (1.f/9.f) + bj, 0.f);
    }
    __syncthreads();

    {
        const int j2 = tid;
        float acc[16];
        const float bv = b_ih[j2];
        #pragma unroll
        for (int m = 0; m < 16; m++) acc[m] = bv;
        for (int k4 = 0; k4 < 32; k4++) {
            float4 wv = *(const float4*)&WTp[k4 * (384*4) + j2 * 4];
            #pragma unroll
            for (int m = 0; m < 16; m++) {
                float4 hv = *(const float4*)&sqb[m * HH + k4 * 4];
                acc[m] = fmaf(hv.x, wv.x, fmaf(hv.y, wv.y, fmaf(hv.z, wv.z, fmaf(hv.w, wv.w, acc[m]))));
            }
        }
        #pragma unroll
        for (int m = 0; m < 16; m++)
            xg[(row0 + m) * 384 + j2] = acc[m];
    }
}

// ---------------------------------------------------------------------------
// Kernel 4: GRU -- R9 structure + pk-fma dots + conflict-free projection.
// BUGFIX vs R12: projection threads with tl >= CHUNK (tid >= 256) were
// reading OOB and stomping outb rows of the NEXT chunk -> absmax 2.1.
// Now guarded with (tl < CHUNK).
// ---------------------------------------------------------------------------
#define CHUNK 32
#define NCH (TTT / CHUNK)
#define HPAD 132
#define XGB_FLOATS (CHUNK * HH * 4)      // 16384 floats = 64 KB

__global__ __launch_bounds__(512)
__attribute__((amdgpu_waves_per_eu(2, 2)))
void gru_kernel(
    const float* __restrict__ xg, const float* __restrict__ W_hh,
    const float* __restrict__ b_hh, const float* __restrict__ Wp,
    const float* __restrict__ bp, float* __restrict__ out)
{
    __shared__ float xgbuf[XGB_FLOATS];          // [tl][i][{xr,xz,xn,pad}]
    __shared__ float houtb[(CHUNK + 1) * HPAD];  // row 0 = carry; rows 1..32 = h(t)
    __shared__ float wps[2 * RHH + 2];           // Wp + bp
    // 64K + 17K + 1K = 82.4 KB -> exactly 1 block/CU

    const int b   = blockIdx.x;
    const int tid = threadIdx.x;
    const int q   = tid & 3;       // k-quarter (quad_perm domain)
    const int i   = tid >> 2;      // hidden unit 0..127

    // ---- preload W_hh slices (rows i, 128+i, 256+i; cols [32q,32q+32)),
    // phase-rotated (p = (m+2q)&7): conflict-free since R6. Stored as v2f
    // pairs so the dots compile to v_pk_fma_f32.
    v2f wr2[16], wz2[16], wn2[16];
    int lof[8];
    {
        const float* br = W_hh + (size_t)i * RHH + q * 32;
        const float* bz = br + (size_t)RHH * RHH;
        const float* bn = bz + (size_t)RHH * RHH;
        #pragma unroll
        for (int m = 0; m < 8; m++) {
            int p = (m + 2 * q) & 7;
            lof[m] = q * 32 + 4 * p;
            float4 v;
            v = *(const float4*)(br + 4*p); wr2[2*m] = (v2f){v.x, v.y}; wr2[2*m+1] = (v2f){v.z, v.w};
            v = *(const float4*)(bz + 4*p); wz2[2*m] = (v2f){v.x, v.y}; wz2[2*m+1] = (v2f){v.z, v.w};
            v = *(const float4*)(bn + 4*p); wn2[2*m] = (v2f){v.x, v.y}; wn2[2*m+1] = (v2f){v.z, v.w};
        }
    }
    const float bhr = b_hh[i];
    const float bhz = b_hh[RHH + i];
    const float bhn = b_hh[2 * RHH + i];

    if (tid < 2 * RHH) wps[tid] = Wp[tid];
    if (tid < 2)       wps[2 * RHH + tid] = bp[tid];
    if (tid < HH)      houtb[tid] = 0.f;          // carry row 0 = h(-1) = 0
    float hprev = 0.f;

    const float* xbase = xg + (size_t)b * TTT * 3 * RHH;
    float* outb = out + (size_t)b * TTT * 2;

    for (int c = 0; c < NCH; c++) {
        // ---- refill xgbuf for chunk c, repacking to [tl][i][{r,z,n,pad}]
        #pragma unroll
        for (int k2 = 0; k2 < 8; k2++) {
            int slot = tid + (k2 << 9);          // 0..4095
            int tl = slot >> 7, ii = slot & 127;
            const float* gsrc = xbase + (size_t)(c * CHUNK + tl) * 384 + ii;
            float4 v;
            v.x = gsrc[0]; v.y = gsrc[128]; v.z = gsrc[256]; v.w = 0.f;
            *(float4*)&xgbuf[slot << 2] = v;
        }
        // ---- project previous chunk: out = houtb[1..32] @ Wp + bp
        // s-rotated slice start kills the 4-way bank alignment (R9's 557K).
        if (c > 0) {
            const int s  = tid & 3;              // 32-float k-slice (quad domain)
            const int cc = (tid >> 2) & 1;
            const int tl = tid >> 3;             // 0..63 -> GUARD to 0..31
            if (tl < CHUNK) {
                const float* hr = &houtb[(tl + 1) * HPAD + s * 32];
                float acc = 0.f;
                #pragma unroll
                for (int jj = 0; jj < 8; jj++) {
                    int mm = 4 * ((jj + 2 * s) & 7);
                    float4 hv = *(const float4*)(hr + mm);
                    int k = s * 32 + mm;
                    acc = fmaf(hv.x, wps[(k+0)*2 + cc],
                          fmaf(hv.y, wps[(k+1)*2 + cc],
                          fmaf(hv.z, wps[(k+2)*2 + cc],
                          fmaf(hv.w, wps[(k+3)*2 + cc], acc))));
                }
                acc = dpp_add<DPP_XOR1>(acc);
                acc = dpp_add<DPP_XOR2>(acc);
                if (s == 0)
                    outb[((c - 1) * CHUNK + tl) * 2 + cc] = acc + wps[2 * RHH + cc];
            }
        }
        __syncthreads();

        // ---- 32 steps
        for (int tl = 0; tl < CHUNK; tl++) {
            const float* hrow = &houtb[tl * HPAD];
            float4 xgv = *(const float4*)&xgbuf[(tl * HH + i) << 2];
            v2f arA = (v2f){0.f, 0.f}, arB = arA, azA = arA, azB = arA, anA = arA, anB = arA;
            #pragma unroll
            for (int m = 0; m < 8; m++) {
                float4 hv = *(const float4*)(hrow + lof[m]);
                v2f h0 = (v2f){hv.x, hv.y};
                v2f h1 = (v2f){hv.z, hv.w};
                if (m & 1) {
                    arB = h0 * wr2[2*m] + arB; arB = h1 * wr2[2*m+1] + arB;
                    azB = h0 * wz2[2*m] + azB; azB = h1 * wz2[2*m+1] + azB;
                    anB = h0 * wn2[2*m] + anB; anB = h1 * wn2[2*m+1] + anB;
                } else {
                    arA = h0 * wr2[2*m] + arA; arA = h1 * wr2[2*m+1] + arA;
                    azA = h0 * wz2[2*m] + azA; azA = h1 * wz2[2*m+1] + azA;
                    anA = h0 * wn2[2*m] + anA; anA = h1 * wn2[2*m+1] + anA;
                }
            }
            v2f arv = arA + arB, azv = azA + azB, anv = anA + anB;
            float ar = arv.x + arv.y;
            float az = azv.x + azv.y;
            float an = anv.x + anv.y;

            // q-reduction: pure VALU DPP butterfly; full sum in ALL lanes
            ar = dpp_add<DPP_XOR1>(ar); ar = dpp_add<DPP_XOR2>(ar);
            az = dpp_add<DPP_XOR1>(az); az = dpp_add<DPP_XOR2>(az);
            an = dpp_add<DPP_XOR1>(an); an = dpp_add<DPP_XOR2>(an);

            // gates (uniform across q-lanes); q==0 publishes
            {
                float sr = xgv.x + ar + bhr;
                float sz = xgv.y + az + bhz;
                float rg = 1.f / (1.f + __expf(-sr));
                float zg = 1.f / (1.f + __expf(-sz));
                float tv = fmaf(rg, an + bhn, xgv.z);
                tv = fminf(fmaxf(tv, -15.f), 15.f);
                float e2 = __expf(-2.f * tv);
                float ng = (1.f - e2) / (1.f + e2);
                hprev = fmaf(zg, hprev, (1.f - zg) * ng);
            }
            if (q == 0) houtb[(tl + 1) * HPAD + i] = hprev;
            __syncthreads();
        }
        // carry: last h of this chunk becomes row 0 for the next
        if (q == 0) houtb[i] = hprev;
        __syncthreads();
    }

    // ---- project the last chunk
    {
        const int s  = tid & 3;
        const int cc = (tid >> 2) & 1;
        const int tl = tid >> 3;
        if (tl < CHUNK) {
            const float* hr = &houtb[(tl + 1) * HPAD + s * 32];
            float acc = 0.f;
            #pragma unroll
            for (int jj = 0; jj < 8; jj++) {
                int mm = 4 * ((jj + 2 * s) & 7);
                float4 hv = *(const float4*)(hr + mm);
                int k = s * 32 + mm;
                acc = fmaf(hv.x, wps[(k+0)*2 + cc],
                      fmaf(hv.y, wps[(k+1)*2 + cc],
                      fmaf(hv.z, wps[(k+2)*2 + cc],
                      fmaf(hv.w, wps[(k+3)*2 + cc], acc))));
            }
            acc = dpp_add<DPP_XOR1>(acc);
            acc = dpp_add<DPP_XOR2>(acc);
            if (s == 0)
                outb[((NCH - 1) * CHUNK + tl) * 2 + cc] = acc + wps[2 * RHH + cc];
        }
    }
}

extern "C" void kernel_launch(void* const* d_in, const int* in_sizes, int n_in,
                              void* d_out, int out_size, void* d_ws, size_t ws_size,
                              hipStream_t stream)
{
    const float* x      = (const float*)d_in[0];
    const int*   eidx   = (const int*)d_in[1];
    const int*   runner = (const int*)d_in[2];
    const float* W1     = (const float*)d_in[3];
    const float* b1     = (const float*)d_in[4];
    const float* W2     = (const float*)d_in[5];
    const float* b2     = (const float*)d_in[6];
    const float* W_ih   = (const float*)d_in[7];
    const float* W_hh   = (const float*)d_in[8];
    const float* b_ih   = (const float*)d_in[9];
    const float* b_hh   = (const float*)d_in[10];
    const float* Wp     = (const float*)d_in[11];
    const float* bp     = (const float*)d_in[12];
    float* out = (float*)d_out;

    float* xg  = (float*)d_ws;                       // 8192*384
    float* WTp = xg + (size_t)GG * 3 * RHH;          // packed W_ih

    pack_wih<<<192, 256, 0, stream>>>(W_ih, WTp);
    gcn_hsum<<<GG, 256, 0, stream>>>(x, eidx, runner, W1, b1, xg);
    seqxg_kernel<<<GG / 16, 384, 0, stream>>>(xg, W2, b2, WTp, b_ih);
    gru_kernel<<<BBB, 512, 0, stream>>>(xg, W_hh, b_hh, Wp, bp, out);
}